// Round 15
// baseline (76.324 us; speedup 1.0000x reference)
//
#include <hip/hip_runtime.h>
#include <hip/hip_bf16.h>
#include <math.h>

// ---- constants mirroring the reference ----
#define TWO_PI_D 6.283185307179586
constexpr int   NOFF  = 32768;
constexpr int   NSAMP = 128;
constexpr int   NRF   = 4;
constexpr int   NSTEP = NRF * NSAMP;   // 512
constexpr float DT    = 3.9e-05f;
constexpr double DTD  = 3.9e-05;
constexpr float R1A   = 1.0f / 1.3f;
constexpr float R2A   = 1.0f / 0.075f;
constexpr float R1B   = 1.0f;
constexpr float R2B   = 30.0f;
constexpr float KBv   = 200.0f;
constexpr float FBv   = 0.01f;
constexpr float KAv   = FBv * KBv;     // 2.0
constexpr float DWB   = 447.0f;

typedef float f32x16 __attribute__((ext_vector_type(16)));

// Wave-uniform table load through the SCALAR pipe (SGPR dest).
#define SLOAD16(dst, p, OFF) \
    asm volatile("s_load_dwordx16 %0, %1, " #OFF : "=s"(dst) : "s"(p))
// lgkmcnt(0) wait with data-dependence fencing (r11/r13-proven pattern).
#define LWAIT(a, b) \
    asm volatile("s_waitcnt lgkmcnt(0)" : "+s"(a), "+s"(b))

struct AccPhD { double a[8]; };        // [sim][rf_block] accumulated phase (f64)

// Per-(sim,step) EXACT RF rotation R = exp(W*DT): Rodrigues about in-plane
// axis n = (-cos ph, -sin ph, 0), angle th = w1*DT. 6 distinct coeffs.
// Stored as 8 floats/step: [r00,r01,r02,r12][r11,r22,0,0].
__global__ void rot_table_kernel(const float* __restrict__ amps,
                                 const float* __restrict__ phases,
                                 AccPhD acc, float4* __restrict__ rt4) {
    int tid = blockIdx.x * blockDim.x + threadIdx.x;   // 0..1023
    if (tid >= 2 * NSTEP) return;
    int sim = tid >> 9;
    int idx = tid & (NSTEP - 1);
    int r   = idx >> 7;
    double ph = -(double)phases[idx] - acc.a[sim * 4 + r];
    double w1 = TWO_PI_D * 42.577 * (double)amps[idx];
    double th = w1 * DTD;
    double sn = sin(th), cs = cos(th), Cc = 1.0 - cs;
    double nx = -cos(ph), ny = -sin(ph);
    rt4[2 * tid]     = make_float4((float)(cs + nx * nx * Cc),
                                   (float)(nx * ny * Cc),
                                   (float)(ny * sn),
                                   (float)(-nx * sn));
    rt4[2 * tid + 1] = make_float4((float)(cs + ny * ny * Cc),
                                   (float)cs, 0.0f, 0.0f);
}

__global__ void init_kernel(unsigned int* g) {
    if (threadIdx.x < 2) g[threadIdx.x] = 0u;
}

// 512-thread blocks -> 2 waves/SIMD on 128 CUs. The waves run IDENTICAL code;
// without skew their dependency stalls align at the same PCs and neither
// fills the other's bubbles (r14: W=2 gave zero wall-time change, VALUBusy
// ~48%). Skew each wave's start by waveid*~256 cyc so stalls interleave.
__global__ __launch_bounds__(512)
__attribute__((amdgpu_waves_per_eu(2, 2)))
void bmc_kernel(
        const float* __restrict__ offsets,
        const float* __restrict__ m_init,
        const float* __restrict__ rt,
        unsigned int* __restrict__ gmax) {
    // ---- wave desync: stagger co-resident waves by ~256 cyc each ----
    {
        int wid = (int)(threadIdx.x >> 6);           // 0..7
        for (int k = 0; k < wid; ++k)
            asm volatile("s_sleep 4");               // ~4*64 cyc per unit
    }

    int sim = (int)(blockIdx.x >> 6);              // 64 blocks per sim
    sim = __builtin_amdgcn_readfirstlane(sim);     // provably wave-uniform
    int o = (int)(blockIdx.x * 512 + threadIdx.x) & (NOFF - 1);

    const float TP  = (float)TWO_PI_D;
    float rf  = sim ? -200.0f : 200.0f;
    float off = offsets[o];
    float dwa = TP * (off - rf);
    float dwb = TP * ((off + DWB) - rf);

    // ---- one-time: drift exponential, EXACTLY block-diagonalized ----
    const float h   = 0.5f * DT;
    const float ca  = -(R2A + KAv), cbv = -(R1A + KAv);
    const float cc  = -(R2B + KBv), cdv = -(R1B + KBv);

    // Taylor-9 of the HALF-step transverse exp (complex 2x2): S = exp(Th)
    float SAr=1, SAi=0, SBr=0, SBi=0, SCr=0, SCi=0, SDr=1, SDi=0;
    {
        const float har = ca * h,  hai = -dwa * h;
        const float hbr = KBv * h;
        const float hcr = KAv * h;
        const float hdr = cc * h,  hdi = -dwb * h;
        float UAr=1, UAi=0, UBr=0, UBi=0, UCr=0, UCi=0, UDr=1, UDi=0;
#pragma unroll
        for (int k = 1; k <= 9; ++k) {
            const float rk = 1.0f / (float)k;
            float NAr = UAr*har - UAi*hai + UBr*hcr;
            float NAi = UAr*hai + UAi*har + UBi*hcr;
            float NBr = UAr*hbr + UBr*hdr - UBi*hdi;
            float NBi = UAi*hbr + UBr*hdi + UBi*hdr;
            float NCr = UCr*har - UCi*hai + UDr*hcr;
            float NCi = UCr*hai + UCi*har + UDi*hcr;
            float NDr = UCr*hbr + UDr*hdr - UDi*hdi;
            float NDi = UCi*hbr + UDr*hdi + UDi*hdr;
            UAr = NAr*rk; UAi = NAi*rk; UBr = NBr*rk; UBi = NBi*rk;
            UCr = NCr*rk; UCi = NCi*rk; UDr = NDr*rk; UDi = NDi*rk;
            SAr += UAr; SAi += UAi; SBr += UBr; SBi += UBi;
            SCr += UCr; SCi += UCi; SDr += UDr; SDi += UDi;
        }
    }
    // FULL-step transverse: F = S*S
    const float trr = SAr + SDr, tri = SAi + SDi;
    const float bcr = SBr*SCr - SBi*SCi, bci = SBr*SCi + SBi*SCr;
    const float Ar = SAr*SAr - SAi*SAi + bcr, Ai = 2.0f*SAr*SAi + bci;
    const float Br = SBr*trr - SBi*tri,       Bi = SBr*tri + SBi*trr;
    const float Cr = SCr*trr - SCi*tri,       Ci = SCr*tri + SCi*trr;
    const float Dr = SDr*SDr - SDi*SDi + bcr, Di = 2.0f*SDr*SDi + bci;

    // Taylor-9 of HALF-step longitudinal augmented exp (2x3)
    float s00=1, s01=0, s02=0, s10=0, s11=1, s12=0;
    {
        const float l00 = cbv*h, l01 = KBv*h, l02 = R1A*h;
        const float l10 = KAv*h, l11 = cdv*h, l12 = R1B*FBv*h;
        float u00=1, u01=0, u02=0, u10=0, u11=1, u12=0;
#pragma unroll
        for (int k = 1; k <= 9; ++k) {
            const float rk = 1.0f / (float)k;
            float n00 = u00*l00 + u01*l10;
            float n01 = u00*l01 + u01*l11;
            float n02 = u00*l02 + u01*l12;
            float n10 = u10*l00 + u11*l10;
            float n11 = u10*l01 + u11*l11;
            float n12 = u10*l02 + u11*l12;
            u00 = n00*rk; u01 = n01*rk; u02 = n02*rk;
            u10 = n10*rk; u11 = n11*rk; u12 = n12*rk;
            s00 += u00; s01 += u01; s02 += u02;
            s10 += u10; s11 += u11; s12 += u12;
        }
    }
    // FULL-step longitudinal: E_L = S2, q = S*qh + qh
    const float eL00 = s00*s00 + s01*s10, eL01 = s00*s01 + s01*s11;
    const float eL10 = s10*s00 + s11*s10, eL11 = s10*s01 + s11*s11;
    const float qL0  = s00*s02 + s01*s12 + s02;
    const float qL1  = s10*s02 + s11*s12 + s12;

    // ---- pre: enter the half-shifted Strang frame: m = Eh * m_init ----
    float x0i = m_init[0], y0i = m_init[1], z0i = m_init[2];
    float x1i = m_init[3], y1i = m_init[4], z1i = m_init[5];
    float m0x = SAr*x0i - SAi*y0i + SBr*x1i - SBi*y1i;
    float m0y = SAr*y0i + SAi*x0i + SBr*y1i + SBi*x1i;
    float m1x = SCr*x0i - SCi*y0i + SDr*x1i - SDi*y1i;
    float m1y = SCr*y0i + SCi*x0i + SDr*y1i + SDi*x1i;
    float m0z = s00*z0i + s01*z1i + s02;
    float m1z = s10*z0i + s11*z1i + s12;
    float lmax = 0.0f;

    // ---- per step: rotation (SGPR coeffs) then split drift. 41 VALU. ----
#define FULL_STEP(g, s)                                                        \
    {                                                                          \
        const float r00 = (g)[8*(s)+0], r01 = (g)[8*(s)+1];                    \
        const float r02 = (g)[8*(s)+2], r12 = (g)[8*(s)+3];                    \
        const float r11 = (g)[8*(s)+4], r22 = (g)[8*(s)+5];                    \
        float xa = fmaf(r00, m0x, fmaf(r01, m0y,  r02 * m0z));                 \
        float ya = fmaf(r01, m0x, fmaf(r11, m0y,  r12 * m0z));                 \
        float za = fmaf(-r02, m0x, fmaf(-r12, m0y, r22 * m0z));                \
        float xb = fmaf(r00, m1x, fmaf(r01, m1y,  r02 * m1z));                 \
        float yb = fmaf(r01, m1x, fmaf(r11, m1y,  r12 * m1z));                 \
        float zb = fmaf(-r02, m1x, fmaf(-r12, m1y, r22 * m1z));                \
        m0x = fmaf(Ar, xa, fmaf(-Ai, ya, fmaf(Br, xb, -Bi * yb)));             \
        m0y = fmaf(Ar, ya, fmaf( Ai, xa, fmaf(Br, yb,  Bi * xb)));             \
        m1x = fmaf(Cr, xa, fmaf(-Ci, ya, fmaf(Dr, xb, -Di * yb)));             \
        m1y = fmaf(Cr, ya, fmaf( Ci, xa, fmaf(Dr, yb,  Di * xb)));             \
        m0z = fmaf(eL00, za, fmaf(eL01, zb, qL0));                             \
        m1z = fmaf(eL10, za, fmaf(eL11, zb, qL1));                             \
        lmax = fmaxf(lmax, fmaf(m0x, m0x, m0y * m0y));                         \
    }
#define COMPUTE4(G0, G1) \
    FULL_STEP(G0, 0) FULL_STEP(G0, 1) FULL_STEP(G1, 0) FULL_STEP(G1, 1)

    // SGPR double buffer: group = 4 steps = 32 floats = 2 x s_load_dwordx16.
    const float* p = rt + (size_t)sim * NSTEP * 8;   // uniform -> SGPR pair
    f32x16 A0, A1, B0, B1;
    SLOAD16(A0, p, 0x0); SLOAD16(A1, p, 0x40);
    LWAIT(A0, A1);
    SLOAD16(B0, p, 0x80); SLOAD16(B1, p, 0xC0);
#pragma unroll 1
    for (int j = 0; j < 63; ++j) {        // 8 steps per iter: groups 2j, 2j+1
        COMPUTE4(A0, A1)
        LWAIT(B0, B1);
        SLOAD16(A0, p, 0x100); SLOAD16(A1, p, 0x140);   // group 2j+2
        COMPUTE4(B0, B1)
        LWAIT(A0, A1);
        SLOAD16(B0, p, 0x180); SLOAD16(B1, p, 0x1C0);   // group 2j+3
        p += 64;                          // advance 2 groups (256 B)
    }
    COMPUTE4(A0, A1)                      // steps 504..507
    LWAIT(B0, B1);
    COMPUTE4(B0, B1)                      // steps 508..511 (half-frame sample)
#undef COMPUTE4
#undef FULL_STEP

    // wave-64 max reduce, then one atomic per wave (sim uniform per wave)
    for (int d = 32; d >= 1; d >>= 1)
        lmax = fmaxf(lmax, __shfl_xor(lmax, d, 64));
    if ((threadIdx.x & 63) == 0)
        atomicMax(gmax + sim, __float_as_uint(lmax));   // all values >= 0

    (void)NSAMP;
}

__global__ void finalize_kernel(const unsigned int* __restrict__ gmax,
                                float* __restrict__ out) {
    int i = threadIdx.x;
    if (i < 2) out[i] = sqrtf(__uint_as_float(gmax[i]));   // float32 output
}

extern "C" void kernel_launch(void* const* d_in, const int* in_sizes, int n_in,
                              void* d_out, int out_size, void* d_ws, size_t ws_size,
                              hipStream_t stream) {
    const float* amps    = (const float*)d_in[0];   // (4,128)
    const float* phases  = (const float*)d_in[1];   // (4,128)
    const float* offsets = (const float*)d_in[2];   // (32768,)
    const float* m_init  = (const float*)d_in[3];   // (6,)
    float* out           = (float*)d_out;           // (2,) float32

    unsigned int* gmax = (unsigned int*)d_ws;                 // 2 slots
    float* rt = (float*)((char*)d_ws + 256);                  // 2*512*8 floats = 32 KB

    // Python-semantics accumulated phase per (sim, rf block), in f64
    AccPhD acc;
    for (int s = 0; s < 2; ++s) {
        double rfo  = s ? -200.0 : 200.0;
        double accp = 0.0;
        for (int r = 0; r < NRF; ++r) {
            acc.a[s * 4 + r] = accp;
            double pd = fmod(3.9e-05 * 128.0 * 360.0 * rfo, 360.0);
            if (pd < 0.0) pd += 360.0;      // Python % semantics
            accp += pd / 180.0 * M_PI;
        }
    }

    init_kernel<<<1, 64, 0, stream>>>(gmax);
    rot_table_kernel<<<4, 256, 0, stream>>>(amps, phases, acc, (float4*)rt);
    bmc_kernel<<<128, 512, 0, stream>>>(offsets, m_init, rt, gmax);
    finalize_kernel<<<1, 64, 0, stream>>>(gmax, out);
}

// Round 16
// 68.573 us; speedup vs baseline: 1.1130x; 1.1130x over previous
//
#include <hip/hip_runtime.h>
#include <hip/hip_bf16.h>
#include <math.h>

// ---- constants mirroring the reference ----
#define TWO_PI_D 6.283185307179586
constexpr int   NOFF  = 32768;
constexpr int   NSAMP = 128;
constexpr int   NRF   = 4;
constexpr int   NSTEP = NRF * NSAMP;   // 512
constexpr float DT    = 3.9e-05f;
constexpr double DTD  = 3.9e-05;
constexpr float R1A   = 1.0f / 1.3f;
constexpr float R2A   = 1.0f / 0.075f;
constexpr float R1B   = 1.0f;
constexpr float R2B   = 30.0f;
constexpr float KBv   = 200.0f;
constexpr float FBv   = 0.01f;
constexpr float KAv   = FBv * KBv;     // 2.0
constexpr float DWB   = 447.0f;

typedef float f32x16 __attribute__((ext_vector_type(16)));

// Wave-uniform table load through the SCALAR pipe (SGPR dest).
#define SLOAD16(dst, p, OFF) \
    asm volatile("s_load_dwordx16 %0, %1, " #OFF : "=s"(dst) : "s"(p))
// lgkmcnt(0) wait with data-dependence fencing (r11/r13-proven pattern).
#define LWAIT(a, b) \
    asm volatile("s_waitcnt lgkmcnt(0)" : "+s"(a), "+s"(b))

struct AccPhD { double a[8]; };        // [sim][rf_block] accumulated phase (f64)

// Per-(sim,step) EXACT RF rotation R = exp(W*DT): Rodrigues about in-plane
// axis n = (-cos ph, -sin ph, 0), angle th = w1*DT. 6 distinct coeffs.
// Stored as 8 floats/step: [r00,r01,r02,r12][r11,r22,0,0].
__global__ void rot_table_kernel(const float* __restrict__ amps,
                                 const float* __restrict__ phases,
                                 AccPhD acc, float4* __restrict__ rt4) {
    int tid = blockIdx.x * blockDim.x + threadIdx.x;   // 0..1023
    if (tid >= 2 * NSTEP) return;
    int sim = tid >> 9;
    int idx = tid & (NSTEP - 1);
    int r   = idx >> 7;
    double ph = -(double)phases[idx] - acc.a[sim * 4 + r];
    double w1 = TWO_PI_D * 42.577 * (double)amps[idx];
    double th = w1 * DTD;
    double sn = sin(th), cs = cos(th), Cc = 1.0 - cs;
    double nx = -cos(ph), ny = -sin(ph);
    rt4[2 * tid]     = make_float4((float)(cs + nx * nx * Cc),
                                   (float)(nx * ny * Cc),
                                   (float)(ny * sn),
                                   (float)(-nx * sn));
    rt4[2 * tid + 1] = make_float4((float)(cs + ny * ny * Cc),
                                   (float)cs, 0.0f, 0.0f);
}

__global__ void init_kernel(unsigned int* g) {
    if (threadIdx.x < 2) g[threadIdx.x] = 0u;
}

__global__ __launch_bounds__(256)
__attribute__((amdgpu_waves_per_eu(1, 1)))
void bmc_kernel(
        const float* __restrict__ offsets,
        const float* __restrict__ m_init,
        const float* __restrict__ rt,
        unsigned int* __restrict__ gmax) {
    int sim = (int)(blockIdx.x >> 7);              // 128 blocks per sim
    sim = __builtin_amdgcn_readfirstlane(sim);     // provably wave-uniform
    int o = (int)(blockIdx.x * 256 + threadIdx.x) & (NOFF - 1);

    const float TP  = (float)TWO_PI_D;
    float rf  = sim ? -200.0f : 200.0f;
    float off = offsets[o];
    float dwa = TP * (off - rf);
    float dwb = TP * ((off + DWB) - rf);

    // ---- one-time: drift exponential, EXACTLY block-diagonalized ----
    // Transverse (m0,m1,m3,m4): za=m0+i*m1, zb=m3+i*m4 -> 2x2 complex exp.
    // Longitudinal (m2,m5): 2x2 real affine exp.
    const float h   = 0.5f * DT;
    const float ca  = -(R2A + KAv), cbv = -(R1A + KAv);
    const float cc  = -(R2B + KBv), cdv = -(R1B + KBv);

    // Taylor-9 of the HALF-step transverse exp (complex 2x2): S = exp(Th)
    float SAr=1, SAi=0, SBr=0, SBi=0, SCr=0, SCi=0, SDr=1, SDi=0;
    {
        const float har = ca * h,  hai = -dwa * h;
        const float hbr = KBv * h;
        const float hcr = KAv * h;
        const float hdr = cc * h,  hdi = -dwb * h;
        float UAr=1, UAi=0, UBr=0, UBi=0, UCr=0, UCi=0, UDr=1, UDi=0;
#pragma unroll
        for (int k = 1; k <= 9; ++k) {
            const float rk = 1.0f / (float)k;
            float NAr = UAr*har - UAi*hai + UBr*hcr;
            float NAi = UAr*hai + UAi*har + UBi*hcr;
            float NBr = UAr*hbr + UBr*hdr - UBi*hdi;
            float NBi = UAi*hbr + UBr*hdi + UBi*hdr;
            float NCr = UCr*har - UCi*hai + UDr*hcr;
            float NCi = UCr*hai + UCi*har + UDi*hcr;
            float NDr = UCr*hbr + UDr*hdr - UDi*hdi;
            float NDi = UCi*hbr + UDr*hdi + UDi*hdr;
            UAr = NAr*rk; UAi = NAi*rk; UBr = NBr*rk; UBi = NBi*rk;
            UCr = NCr*rk; UCi = NCi*rk; UDr = NDr*rk; UDi = NDi*rk;
            SAr += UAr; SAi += UAi; SBr += UBr; SBi += UBi;
            SCr += UCr; SCi += UCi; SDr += UDr; SDi += UDi;
        }
    }
    // FULL-step transverse: F = S*S
    const float trr = SAr + SDr, tri = SAi + SDi;
    const float bcr = SBr*SCr - SBi*SCi, bci = SBr*SCi + SBi*SCr;
    const float Ar = SAr*SAr - SAi*SAi + bcr, Ai = 2.0f*SAr*SAi + bci;
    const float Br = SBr*trr - SBi*tri,       Bi = SBr*tri + SBi*trr;
    const float Cr = SCr*trr - SCi*tri,       Ci = SCr*tri + SCi*trr;
    const float Dr = SDr*SDr - SDi*SDi + bcr, Di = 2.0f*SDr*SDi + bci;

    // Taylor-9 of HALF-step longitudinal augmented exp (2x3)
    float s00=1, s01=0, s02=0, s10=0, s11=1, s12=0;
    {
        const float l00 = cbv*h, l01 = KBv*h, l02 = R1A*h;
        const float l10 = KAv*h, l11 = cdv*h, l12 = R1B*FBv*h;
        float u00=1, u01=0, u02=0, u10=0, u11=1, u12=0;
#pragma unroll
        for (int k = 1; k <= 9; ++k) {
            const float rk = 1.0f / (float)k;
            float n00 = u00*l00 + u01*l10;
            float n01 = u00*l01 + u01*l11;
            float n02 = u00*l02 + u01*l12;
            float n10 = u10*l00 + u11*l10;
            float n11 = u10*l01 + u11*l11;
            float n12 = u10*l02 + u11*l12;
            u00 = n00*rk; u01 = n01*rk; u02 = n02*rk;
            u10 = n10*rk; u11 = n11*rk; u12 = n12*rk;
            s00 += u00; s01 += u01; s02 += u02;
            s10 += u10; s11 += u11; s12 += u12;
        }
    }
    // FULL-step longitudinal: E_L = S2, q = S*qh + qh
    const float eL00 = s00*s00 + s01*s10, eL01 = s00*s01 + s01*s11;
    const float eL10 = s10*s00 + s11*s10, eL11 = s10*s01 + s11*s11;
    const float qL0  = s00*s02 + s01*s12 + s02;
    const float qL1  = s10*s02 + s11*s12 + s12;

    // ---- pre: enter the half-shifted Strang frame: m = Eh * m_init ----
    float x0i = m_init[0], y0i = m_init[1], z0i = m_init[2];
    float x1i = m_init[3], y1i = m_init[4], z1i = m_init[5];
    float m0x = SAr*x0i - SAi*y0i + SBr*x1i - SBi*y1i;
    float m0y = SAr*y0i + SAi*x0i + SBr*y1i + SBi*x1i;
    float m1x = SCr*x0i - SCi*y0i + SDr*x1i - SDi*y1i;
    float m1y = SCr*y0i + SCi*x0i + SDr*y1i + SDi*x1i;
    float m0z = s00*z0i + s01*z1i + s02;
    float m1z = s10*z0i + s11*z1i + s12;
    float lmax = 0.0f;

    // ---- per step: rotation (depth 3) + TREE drift (depth 3) = 6-level
    // critical path (r13's nested drift was 6 deep -> 9-level path; the
    // 316 cyc/step wall tracked that path across every null experiment).
    // Tree: m0x' = fma(Ar,xa, -Ai*ya) + fma(Br,xb, -Bi*yb)  (exact reassoc)
#define FULL_STEP(g, s)                                                        \
    {                                                                          \
        const float r00 = (g)[8*(s)+0], r01 = (g)[8*(s)+1];                    \
        const float r02 = (g)[8*(s)+2], r12 = (g)[8*(s)+3];                    \
        const float r11 = (g)[8*(s)+4], r22 = (g)[8*(s)+5];                    \
        float xa = fmaf(r00, m0x, fmaf(r01, m0y,  r02 * m0z));                 \
        float ya = fmaf(r01, m0x, fmaf(r11, m0y,  r12 * m0z));                 \
        float za = fmaf(-r02, m0x, fmaf(-r12, m0y, r22 * m0z));                \
        float xb = fmaf(r00, m1x, fmaf(r01, m1y,  r02 * m1z));                 \
        float yb = fmaf(r01, m1x, fmaf(r11, m1y,  r12 * m1z));                 \
        float zb = fmaf(-r02, m1x, fmaf(-r12, m1y, r22 * m1z));                \
        float t0x = fmaf(Ar, xa, -Ai * ya);                                    \
        float u0x = fmaf(Br, xb, -Bi * yb);                                    \
        float t0y = fmaf(Ar, ya,  Ai * xa);                                    \
        float u0y = fmaf(Br, yb,  Bi * xb);                                    \
        float t1x = fmaf(Cr, xa, -Ci * ya);                                    \
        float u1x = fmaf(Dr, xb, -Di * yb);                                    \
        float t1y = fmaf(Cr, ya,  Ci * xa);                                    \
        float u1y = fmaf(Dr, yb,  Di * xb);                                    \
        float z0n = fmaf(eL00, za, fmaf(eL01, zb, qL0));                       \
        float z1n = fmaf(eL10, za, fmaf(eL11, zb, qL1));                       \
        m0x = t0x + u0x;  m0y = t0y + u0y;                                     \
        m1x = t1x + u1x;  m1y = t1y + u1y;                                     \
        m0z = z0n;        m1z = z1n;                                           \
        lmax = fmaxf(lmax, fmaf(m0x, m0x, m0y * m0y));                         \
    }
#define COMPUTE4(G0, G1) \
    FULL_STEP(G0, 0) FULL_STEP(G0, 1) FULL_STEP(G1, 0) FULL_STEP(G1, 1)

    // SGPR double buffer: group = 4 steps = 32 floats = 2 x s_load_dwordx16.
    const float* p = rt + (size_t)sim * NSTEP * 8;   // uniform -> SGPR pair
    f32x16 A0, A1, B0, B1;
    SLOAD16(A0, p, 0x0); SLOAD16(A1, p, 0x40);
    LWAIT(A0, A1);
    SLOAD16(B0, p, 0x80); SLOAD16(B1, p, 0xC0);
#pragma unroll 1
    for (int j = 0; j < 63; ++j) {        // 8 steps per iter: groups 2j, 2j+1
        COMPUTE4(A0, A1)
        LWAIT(B0, B1);
        SLOAD16(A0, p, 0x100); SLOAD16(A1, p, 0x140);   // group 2j+2
        COMPUTE4(B0, B1)
        LWAIT(A0, A1);
        SLOAD16(B0, p, 0x180); SLOAD16(B1, p, 0x1C0);   // group 2j+3
        p += 64;                          // advance 2 groups (256 B)
    }
    COMPUTE4(A0, A1)                      // steps 504..507
    LWAIT(B0, B1);
    COMPUTE4(B0, B1)                      // steps 508..511 (half-frame sample)
#undef COMPUTE4
#undef FULL_STEP

    // wave-64 max reduce, then one atomic per wave (sim uniform per wave)
    for (int d = 32; d >= 1; d >>= 1)
        lmax = fmaxf(lmax, __shfl_xor(lmax, d, 64));
    if ((threadIdx.x & 63) == 0)
        atomicMax(gmax + sim, __float_as_uint(lmax));   // all values >= 0

    (void)NSAMP;
}

__global__ void finalize_kernel(const unsigned int* __restrict__ gmax,
                                float* __restrict__ out) {
    int i = threadIdx.x;
    if (i < 2) out[i] = sqrtf(__uint_as_float(gmax[i]));   // float32 output
}

extern "C" void kernel_launch(void* const* d_in, const int* in_sizes, int n_in,
                              void* d_out, int out_size, void* d_ws, size_t ws_size,
                              hipStream_t stream) {
    const float* amps    = (const float*)d_in[0];   // (4,128)
    const float* phases  = (const float*)d_in[1];   // (4,128)
    const float* offsets = (const float*)d_in[2];   // (32768,)
    const float* m_init  = (const float*)d_in[3];   // (6,)
    float* out           = (float*)d_out;           // (2,) float32

    unsigned int* gmax = (unsigned int*)d_ws;                 // 2 slots
    float* rt = (float*)((char*)d_ws + 256);                  // 2*512*8 floats = 32 KB

    // Python-semantics accumulated phase per (sim, rf block), in f64
    AccPhD acc;
    for (int s = 0; s < 2; ++s) {
        double rfo  = s ? -200.0 : 200.0;
        double accp = 0.0;
        for (int r = 0; r < NRF; ++r) {
            acc.a[s * 4 + r] = accp;
            double pd = fmod(3.9e-05 * 128.0 * 360.0 * rfo, 360.0);
            if (pd < 0.0) pd += 360.0;      // Python % semantics
            accp += pd / 180.0 * M_PI;
        }
    }

    init_kernel<<<1, 64, 0, stream>>>(gmax);
    rot_table_kernel<<<4, 256, 0, stream>>>(amps, phases, acc, (float4*)rt);
    bmc_kernel<<<(2 * NOFF) / 256, 256, 0, stream>>>(offsets, m_init, rt, gmax);
    finalize_kernel<<<1, 64, 0, stream>>>(gmax, out);
}